// Round 10
// baseline (187.234 us; speedup 1.0000x reference)
//
#include <hip/hip_runtime.h>
#include <hip/hip_bf16.h>
#include <math.h>

#define DMODEL 1024
#define NHEADS 16
#define DKH    64
#define BATCH  2
#define SEQ    2048
#define MROWS  (BATCH * SEQ)   // 4096
#define LOG2E  1.4426950408889634f

typedef __bf16 bf16_t;
typedef bf16_t bf16x8 __attribute__((ext_vector_type(8)));
typedef bf16_t bf16x4 __attribute__((ext_vector_type(4)));
typedef float  floatx4 __attribute__((ext_vector_type(4)));

// async global->LDS, 16B per lane
__device__ __forceinline__ void glds16(const bf16_t* g, bf16_t* l) {
    __builtin_amdgcn_global_load_lds((__attribute__((address_space(1))) unsigned*)(g),
                                     (__attribute__((address_space(3))) unsigned*)(l),
                                     16, 0, 0);
}

// ---------------------------------------------------------------- prep: cast x (z=0) + transpose W (z=1..4)
__global__ void prep_kernel(const float* __restrict__ x,
                            const float* __restrict__ W0, const float* __restrict__ W1,
                            const float* __restrict__ W2, const float* __restrict__ W3,
                            bf16_t* __restrict__ xb, bf16_t* __restrict__ Wt) {
    __shared__ float t[32][33];
    int bx = blockIdx.x, by = blockIdx.y, z = blockIdx.z;
    int tx = threadIdx.x, ty = threadIdx.y;
    if (z == 0) {   // cast x: 128 rows x 32 cols per block, float4-vectorized
        int tid = ty * 32 + tx;
#pragma unroll
        for (int k = 0; k < 4; ++k) {
            int slot = k * 256 + tid;
            int row = by * 128 + (slot >> 3);
            int col = bx * 32 + (slot & 7) * 4;
            float4 v = *(const float4*)&x[(size_t)row * DMODEL + col];
            bf16x4 o = {(bf16_t)v.x, (bf16_t)v.y, (bf16_t)v.z, (bf16_t)v.w};
            *(bf16x4*)&xb[(size_t)row * DMODEL + col] = o;
        }
        return;
    }
    const float* W = (z == 1) ? W0 : (z == 2) ? W1 : (z == 3) ? W2 : W3;
    bf16_t* dst = Wt + (size_t)(z - 1) * DMODEL * DMODEL;
#pragma unroll
    for (int i = 0; i < 32; i += 8)
        t[ty + i][tx] = W[(size_t)(by * 32 + ty + i) * DMODEL + bx * 32 + tx];
    __syncthreads();
#pragma unroll
    for (int i = 0; i < 32; i += 8)
        dst[(size_t)(bx * 32 + ty + i) * DMODEL + by * 32 + tx] = (bf16_t)t[tx][ty + i];
}

// ---------------------------------------------------------------- fused QKV GEMM, 128x128, BK=64
// Epilogue assembles outputs in the dead As/Bs LDS, then streams 1KB-coalesced bursts.
// ALL THREE outputs frag-major: ((bh*32 + tile)*8 + sub)*512 + lane*8 + j
__global__ __launch_bounds__(256) void gemm_qkv_kernel(const bf16_t* __restrict__ A,
                                                       const bf16_t* __restrict__ Bt,
                                                       bf16_t* __restrict__ Qfb,
                                                       bf16_t* __restrict__ Kfb,
                                                       bf16_t* __restrict__ Vfb) {
    __shared__ bf16_t sm[16384];
    bf16_t* As = sm;
    bf16_t* Bs = sm + 8192;
    int tid = threadIdx.x;
    int w = tid >> 6, l = tid & 63, g = l >> 4, lm = l & 15;
    int wr = w >> 1, wc = w & 1;
    int m0 = blockIdx.y * 128, n0 = blockIdx.x * 128;
    int r8 = l >> 3, s8 = l & 7, cw = s8 ^ r8;

    floatx4 acc[4][4];
#pragma unroll
    for (int i = 0; i < 4; ++i)
#pragma unroll
        for (int j = 0; j < 4; ++j) { floatx4 z = {0.f, 0.f, 0.f, 0.f}; acc[i][j] = z; }

    const bf16_t* Ag = A  + (size_t)(m0 + w * 32 + r8) * DMODEL + cw * 8;
    const bf16_t* Bg = Bt + (size_t)(n0 + w * 32 + r8) * DMODEL + cw * 8;

    for (int k0 = 0; k0 < DMODEL; k0 += 64) {
        __syncthreads();
#pragma unroll
        for (int j = 0; j < 4; ++j) {
            glds16(Ag + (size_t)j * 8 * DMODEL + k0, &As[(w * 32 + j * 8) * 64]);
            glds16(Bg + (size_t)j * 8 * DMODEL + k0, &Bs[(w * 32 + j * 8) * 64]);
        }
        __syncthreads();
#pragma unroll
        for (int kk = 0; kk < 2; ++kk) {
            bf16x8 af[4], bfr[4];
            int c = kk * 4 + g;
            int sw = (c ^ (lm & 7)) * 8;
#pragma unroll
            for (int i = 0; i < 4; ++i) {
                af[i]  = *(const bf16x8*)&As[(wr * 64 + i * 16 + lm) * 64 + sw];
                bfr[i] = *(const bf16x8*)&Bs[(wc * 64 + i * 16 + lm) * 64 + sw];
            }
#pragma unroll
            for (int i = 0; i < 4; ++i)
#pragma unroll
                for (int j = 0; j < 4; ++j)
                    acc[i][j] = __builtin_amdgcn_mfma_f32_16x16x32_bf16(af[i], bfr[j], acc[i][j], 0, 0, 0);
        }
    }

    __syncthreads();
    int mat = n0 >> 10;
    int headb = (n0 & 1023) >> 6;
    int b = m0 >> 11;
    int ktb = (m0 & 2047) >> 6;
    float scale = (mat == 0) ? (0.125f * LOG2E) : 1.0f;

    if (mat <= 1) {
#pragma unroll
        for (int i = 0; i < 4; ++i)
#pragma unroll
            for (int j = 0; j < 4; ++j) {
                int d = j * 16 + lm;
                int base = (wc * 2 + wr) * 4096 + (i * 2 + (d >> 5)) * 512 + ((d >> 3) & 3) * 128 + (d & 7);
#pragma unroll
                for (int r = 0; r < 4; ++r)
                    sm[base + (g * 4 + r) * 8] = (bf16_t)(acc[i][j][r] * scale);
            }
    } else {
#pragma unroll
        for (int i = 0; i < 4; ++i)
#pragma unroll
            for (int j = 0; j < 4; ++j) {
                int base = (wc * 2 + wr) * 4096 + (j * 2 + (i >> 1)) * 512 +
                           (((i & 1) * 2 + (g >> 1)) * 16 + lm) * 8 + (g & 1) * 4;
                bf16x4 pk = {(bf16_t)acc[i][j][0], (bf16_t)acc[i][j][1],
                             (bf16_t)acc[i][j][2], (bf16_t)acc[i][j][3]};
                *(bf16x4*)&sm[base] = pk;
            }
    }
    __syncthreads();
    bf16_t* outbuf = (mat == 0) ? Qfb : (mat == 1) ? Kfb : Vfb;
#pragma unroll
    for (int rep = 0; rep < 8; ++rep) {
        int idx = rep * 256 + tid;
        int c = idx >> 9;
        int off = (idx & 511) * 8;
        int bh2 = b * NHEADS + headb + (c >> 1);
        int kt = ktb + (c & 1);
        *(bf16x8*)(outbuf + ((size_t)bh2 * 32 + kt) * 4096 + off) = *(const bf16x8*)&sm[c * 4096 + off];
    }
}

// ---------------------------------------------------------------- O-proj GEMM, 64x128 tile
__global__ __launch_bounds__(256) void gemmO_kernel(const bf16_t* __restrict__ A,
                                                    const bf16_t* __restrict__ Bt,
                                                    float* __restrict__ outp) {
    __shared__ bf16_t As[64 * 64];
    __shared__ bf16_t Bs[128 * 64];
    int tid = threadIdx.x;
    int w = tid >> 6, l = tid & 63, g = l >> 4, lm = l & 15;
    int wr = w & 1, wc = w >> 1;
    int m0 = blockIdx.y * 64, n0 = blockIdx.x * 128;
    int r8 = l >> 3, s8 = l & 7, cw = s8 ^ r8;

    floatx4 acc[2][4];
#pragma unroll
    for (int i = 0; i < 2; ++i)
#pragma unroll
        for (int j = 0; j < 4; ++j) { floatx4 z = {0.f, 0.f, 0.f, 0.f}; acc[i][j] = z; }

    const bf16_t* Ag = A  + (size_t)(m0 + w * 16 + r8) * DMODEL + cw * 8;
    const bf16_t* Bg = Bt + (size_t)(n0 + w * 32 + r8) * DMODEL + cw * 8;

    for (int k0 = 0; k0 < DMODEL; k0 += 64) {
        __syncthreads();
#pragma unroll
        for (int j = 0; j < 2; ++j)
            glds16(Ag + (size_t)j * 8 * DMODEL + k0, &As[(w * 16 + j * 8) * 64]);
#pragma unroll
        for (int j = 0; j < 4; ++j)
            glds16(Bg + (size_t)j * 8 * DMODEL + k0, &Bs[(w * 32 + j * 8) * 64]);
        __syncthreads();
#pragma unroll
        for (int kk = 0; kk < 2; ++kk) {
            bf16x8 af[2], bfr[4];
            int c = kk * 4 + g;
            int sw = (c ^ (lm & 7)) * 8;
#pragma unroll
            for (int i = 0; i < 2; ++i)
                af[i] = *(const bf16x8*)&As[(wr * 32 + i * 16 + lm) * 64 + sw];
#pragma unroll
            for (int j = 0; j < 4; ++j)
                bfr[j] = *(const bf16x8*)&Bs[(wc * 64 + j * 16 + lm) * 64 + sw];
#pragma unroll
            for (int i = 0; i < 2; ++i)
#pragma unroll
                for (int j = 0; j < 4; ++j)
                    acc[i][j] = __builtin_amdgcn_mfma_f32_16x16x32_bf16(af[i], bfr[j], acc[i][j], 0, 0, 0);
        }
    }

#pragma unroll
    for (int i = 0; i < 2; ++i)
#pragma unroll
        for (int j = 0; j < 4; ++j) {
            int nc = n0 + wc * 64 + j * 16 + lm;
            int mb = m0 + wr * 32 + i * 16 + g * 4;
#pragma unroll
            for (int r = 0; r < 4; ++r)
                outp[(size_t)(mb + r) * DMODEL + nc] = acc[i][j][r];
        }
}

// ---------------------------------------------------------------- fused flash attention
// grid (32 bh, 32 qblk), block 256 = 4 waves = 2 q-groups (32q each) x 2 key-splits.
// Wave: 32 q x 1024 keys (16 iters of 64 keys, half-tile pipelined).
// Per-wave regs ~164 -> __launch_bounds__(256,3) targets 3 waves/SIMD (cap 170).
// R6 lesson: never set a bound whose cap is far below the live set (cap128/need240 spilled 1.5GB).
__global__ __launch_bounds__(256, 3) void attn_kernel(const bf16_t* __restrict__ Qf,
                                                      const bf16_t* __restrict__ Kf,
                                                      const bf16_t* __restrict__ Vf,
                                                      bf16_t* __restrict__ Cc) {
    __shared__ __align__(16) char smem[26880];
    bf16_t* Ps   = (bf16_t*)smem;            // loop: [w][32*40] half-P tiles (wave-private)
    float*  Mbuf = (float*)smem;             // merge: [qw][32*68] fp32 partials (aliased)
    float*  Lbuf = (float*)(smem + 17408);   // [qw][32] lsum partials
    bf16_t* Ct   = (bf16_t*)(smem + 17664);  // [qw][32*72] store-assembly

    int tid = threadIdx.x;
    int w = tid >> 6, l = tid & 63, g = l >> 4, lm = l & 15;
    int qw = w >> 1, ks = w & 1;
    int bh = blockIdx.x, b = bh >> 4, h = bh & 15;
    int q0 = blockIdx.y * 64;

    const bf16_t* Qfh = Qf + ((size_t)bh * 32 + (q0 >> 6)) * 4096 + l * 8;
    const bf16_t* Kfh = Kf + (size_t)bh * 32 * 4096 + l * 8;
    const bf16_t* Vfh = Vf + (size_t)bh * 32 * 4096 + l * 8;

    // Q B-frags for this wave's 32 q rows (nt' 0..1 -> global sub qw*4 + nt*2 + kk)
    bf16x8 qf[2][2];
#pragma unroll
    for (int nt = 0; nt < 2; ++nt)
#pragma unroll
        for (int kk = 0; kk < 2; ++kk)
            qf[nt][kk] = *(const bf16x8*)(Qfh + (qw * 4 + nt * 2 + kk) * 512);

    floatx4 oacc[4][2];
#pragma unroll
    for (int dt = 0; dt < 4; ++dt)
#pragma unroll
        for (int nt = 0; nt < 2; ++nt) { floatx4 z = {0.f, 0.f, 0.f, 0.f}; oacc[dt][nt] = z; }
    float lsum[2] = {0.f, 0.f};

    int kt0 = ks * 16;
    bf16x8 kfa[2][2], kfb[2][2], vfa[4], vfb[4];
    {
        const bf16_t* Kb0 = Kfh + (size_t)kt0 * 4096;
#pragma unroll
        for (int m2 = 0; m2 < 2; ++m2)
#pragma unroll
            for (int kk = 0; kk < 2; ++kk)
                kfa[m2][kk] = *(const bf16x8*)(Kb0 + (m2 * 2 + kk) * 512);
    }

    for (int it = 0; it < 16; ++it) {
        const bf16_t* Tb = Kfh + (size_t)(kt0 + it) * 4096;
        const bf16_t* Vb = Vfh + (size_t)(kt0 + it) * 4096;
        const bf16_t* Tn = Kfh + (size_t)(kt0 + ((it < 15) ? it + 1 : 0)) * 4096;

        // loads: V half0 (keys 0..31), K half1 (keys 32..63)
#pragma unroll
        for (int dt = 0; dt < 4; ++dt) vfa[dt] = *(const bf16x8*)(Vb + (dt * 2 + 0) * 512);
#pragma unroll
        for (int m2 = 0; m2 < 2; ++m2)
#pragma unroll
            for (int kk = 0; kk < 2; ++kk)
                kfb[m2][kk] = *(const bf16x8*)(Tb + (4 + m2 * 2 + kk) * 512);

        // S half0: S^T[key 0..31][q 0..31]
        floatx4 sa[2][2];
#pragma unroll
        for (int m2 = 0; m2 < 2; ++m2)
#pragma unroll
            for (int nt = 0; nt < 2; ++nt) { floatx4 z = {0.f, 0.f, 0.f, 0.f}; sa[m2][nt] = z; }
#pragma unroll
        for (int kk = 0; kk < 2; ++kk)
#pragma unroll
            for (int m2 = 0; m2 < 2; ++m2)
#pragma unroll
                for (int nt = 0; nt < 2; ++nt)
                    sa[m2][nt] = __builtin_amdgcn_mfma_f32_16x16x32_bf16(kfa[m2][kk], qf[nt][kk], sa[m2][nt], 0, 0, 0);

        // loads: V half1, K half0 of next tile
#pragma unroll
        for (int dt = 0; dt < 4; ++dt) vfb[dt] = *(const bf16x8*)(Vb + (dt * 2 + 1) * 512);
#pragma unroll
        for (int m2 = 0; m2 < 2; ++m2)
#pragma unroll
            for (int kk = 0; kk < 2; ++kk)
                kfa[m2][kk] = *(const bf16x8*)(Tn + (m2 * 2 + kk) * 512);

        // S half1 — independent of exp(half0)
        floatx4 sb[2][2];
#pragma unroll
        for (int m2 = 0; m2 < 2; ++m2)
#pragma unroll
            for (int nt = 0; nt < 2; ++nt) { floatx4 z = {0.f, 0.f, 0.f, 0.f}; sb[m2][nt] = z; }
#pragma unroll
        for (int kk = 0; kk < 2; ++kk)
#pragma unroll
            for (int m2 = 0; m2 < 2; ++m2)
#pragma unroll
                for (int nt = 0; nt < 2; ++nt)
                    sb[m2][nt] = __builtin_amdgcn_mfma_f32_16x16x32_bf16(kfb[m2][kk], qf[nt][kk], sb[m2][nt], 0, 0, 0);

        // --- half0: exp + P write + PV ---
#pragma unroll
        for (int m2 = 0; m2 < 2; ++m2)
#pragma unroll
            for (int nt = 0; nt < 2; ++nt) {
                float p0 = __builtin_amdgcn_exp2f(sa[m2][nt][0]);
                float p1 = __builtin_amdgcn_exp2f(sa[m2][nt][1]);
                float p2 = __builtin_amdgcn_exp2f(sa[m2][nt][2]);
                float p3 = __builtin_amdgcn_exp2f(sa[m2][nt][3]);
                lsum[nt] += (p0 + p1) + (p2 + p3);
                bf16x4 pk = {(bf16_t)p0, (bf16_t)p1, (bf16_t)p2, (bf16_t)p3};
                *(bf16x4*)&Ps[w * 1280 + (nt * 16 + lm) * 40 + m2 * 16 + g * 4] = pk;
            }
        {
            bf16x8 bp[2];
#pragma unroll
            for (int nt = 0; nt < 2; ++nt)
                bp[nt] = *(const bf16x8*)&Ps[w * 1280 + (nt * 16 + lm) * 40 + g * 8];
#pragma unroll
            for (int dt = 0; dt < 4; ++dt)
#pragma unroll
                for (int nt = 0; nt < 2; ++nt)
                    oacc[dt][nt] = __builtin_amdgcn_mfma_f32_16x16x32_bf16(vfa[dt], bp[nt], oacc[dt][nt], 0, 0, 0);
        }

        // --- half1: exp + P write + PV ---
#pragma unroll
        for (int m2 = 0; m2 < 2; ++m2)
#pragma unroll
            for (int nt = 0; nt < 2; ++nt) {
                float p0 = __builtin_amdgcn_exp2f(sb[m2][nt][0]);
                float p1 = __builtin_amdgcn_exp2f(sb[m2][nt][1]);
                float p2 = __builtin_amdgcn_exp2f(sb[m2][nt][2]);
                float p3 = __builtin_amdgcn_exp2f(sb[m2][nt][3]);
                lsum[nt] += (p0 + p1) + (p2 + p3);
                bf16x4 pk = {(bf16_t)p0, (bf16_t)p1, (bf16_t)p2, (bf16_t)p3};
                *(bf16x4*)&Ps[w * 1280 + (nt * 16 + lm) * 40 + m2 * 16 + g * 4] = pk;
            }
        {
            bf16x8 bp[2];
#pragma unroll
            for (int nt = 0; nt < 2; ++nt)
                bp[nt] = *(const bf16x8*)&Ps[w * 1280 + (nt * 16 + lm) * 40 + g * 8];
#pragma unroll
            for (int dt = 0; dt < 4; ++dt)
#pragma unroll
                for (int nt = 0; nt < 2; ++nt)
                    oacc[dt][nt] = __builtin_amdgcn_mfma_f32_16x16x32_bf16(vfb[dt], bp[nt], oacc[dt][nt], 0, 0, 0);
        }
    }

    // reduce lsum within wave across g-groups (q = nt*16+lm fixed per lane)
#pragma unroll
    for (int nt = 0; nt < 2; ++nt) {
        float s = lsum[nt];
        s += __shfl_xor(s, 16, 64);
        s += __shfl_xor(s, 32, 64);
        lsum[nt] = s;
    }

    // merge the 2 key-split partials per q-group through LDS
    __syncthreads();           // all waves done with Ps (Mbuf aliases it)
    if (ks == 1) {
#pragma unroll
        for (int dt = 0; dt < 4; ++dt)
#pragma unroll
            for (int nt = 0; nt < 2; ++nt)
                *(floatx4*)&Mbuf[qw * 2176 + (nt * 16 + lm) * 68 + dt * 16 + g * 4] = oacc[dt][nt];
        if (g == 0)
#pragma unroll
            for (int nt = 0; nt < 2; ++nt)
                Lbuf[qw * 32 + nt * 16 + lm] = lsum[nt];
    }
    __syncthreads();
    if (ks == 0) {
        float linv[2];
#pragma unroll
        for (int nt = 0; nt < 2; ++nt)
            linv[nt] = 1.0f / (lsum[nt] + Lbuf[qw * 32 + nt * 16 + lm]);
#pragma unroll
        for (int dt = 0; dt < 4; ++dt)
#pragma unroll
            for (int nt = 0; nt < 2; ++nt) {
                floatx4 part = *(const floatx4*)&Mbuf[qw * 2176 + (nt * 16 + lm) * 68 + dt * 16 + g * 4];
                bf16x4 pk = {(bf16_t)((oacc[dt][nt][0] + part[0]) * linv[nt]),
                             (bf16_t)((oacc[dt][nt][1] + part[1]) * linv[nt]),
                             (bf16_t)((oacc[dt][nt][2] + part[2]) * linv[nt]),
                             (bf16_t)((oacc[dt][nt][3] + part[3]) * linv[nt])};
                *(bf16x4*)&Ct[qw * 2304 + (nt * 16 + lm) * 72 + dt * 16 + g * 4] = pk;
            }
        // coalesced row stores: 32 rows x 8 chunks of 8 elems = 256 slots, 4 reps
#pragma unroll
        for (int rep = 0; rep < 4; ++rep) {
            int idx = rep * 64 + l;
            int row = idx >> 3, dp = idx & 7;
            bf16x8 v = *(const bf16x8*)&Ct[qw * 2304 + row * 72 + dp * 8];
            *(bf16x8*)&Cc[((size_t)(b * SEQ + q0 + qw * 32 + row)) * DMODEL + h * DKH + dp * 8] = v;
        }
    }
}

// ----------------------------------------------------------------------------
extern "C" void kernel_launch(void* const* d_in, const int* in_sizes, int n_in,
                              void* d_out, int out_size, void* d_ws, size_t ws_size,
                              hipStream_t stream) {
    const float* x  = (const float*)d_in[0];
    const float* Wq = (const float*)d_in[1];
    const float* Wk = (const float*)d_in[2];
    const float* Wv = (const float*)d_in[3];
    const float* Wo = (const float*)d_in[4];

    const size_t NX = (size_t)MROWS * DMODEL;
    const size_t NW = (size_t)DMODEL * DMODEL;
    bf16_t* ws  = (bf16_t*)d_ws;
    bf16_t* xb  = ws;            // x bf16
    bf16_t* Wt  = xb + NX;       // W^T x4 contiguous: q,k,v,o
    bf16_t* Wto = Wt + 3 * NW;
    bf16_t* Qfb = Wt + 4 * NW;   // Q frag-major (B-operand), scaled log2(e)/8
    bf16_t* Kfb = Qfb + NX;      // K frag-major
    bf16_t* Vfb = Kfb + NX;      // V frag-major
    bf16_t* Cc  = Vfb + NX;      // concat

    prep_kernel<<<dim3(32, 32, 5), dim3(32, 8), 0, stream>>>(x, Wq, Wk, Wv, Wo, xb, Wt);

    gemm_qkv_kernel<<<dim3(3 * DMODEL / 128, MROWS / 128), 256, 0, stream>>>(xb, Wt, Qfb, Kfb, Vfb);

    attn_kernel<<<dim3(BATCH * NHEADS, SEQ / 64), 256, 0, stream>>>(Qfb, Kfb, Vfb, Cc);

    gemmO_kernel<<<dim3(DMODEL / 128, MROWS / 64), 256, 0, stream>>>(Cc, Wto, (float*)d_out);
}

// Round 11
// 182.383 us; speedup vs baseline: 1.0266x; 1.0266x over previous
//
#include <hip/hip_runtime.h>
#include <hip/hip_bf16.h>
#include <math.h>

#define DMODEL 1024
#define NHEADS 16
#define DKH    64
#define BATCH  2
#define SEQ    2048
#define MROWS  (BATCH * SEQ)   // 4096
#define LOG2E  1.4426950408889634f

typedef __bf16 bf16_t;
typedef bf16_t bf16x8 __attribute__((ext_vector_type(8)));
typedef bf16_t bf16x4 __attribute__((ext_vector_type(4)));
typedef float  floatx4 __attribute__((ext_vector_type(4)));

// async global->LDS, 16B per lane
__device__ __forceinline__ void glds16(const bf16_t* g, bf16_t* l) {
    __builtin_amdgcn_global_load_lds((__attribute__((address_space(1))) unsigned*)(g),
                                     (__attribute__((address_space(3))) unsigned*)(l),
                                     16, 0, 0);
}

// ---------------------------------------------------------------- prep: cast x (z=0) + transpose W (z=1..4)
__global__ void prep_kernel(const float* __restrict__ x,
                            const float* __restrict__ W0, const float* __restrict__ W1,
                            const float* __restrict__ W2, const float* __restrict__ W3,
                            bf16_t* __restrict__ xb, bf16_t* __restrict__ Wt) {
    __shared__ float t[32][33];
    int bx = blockIdx.x, by = blockIdx.y, z = blockIdx.z;
    int tx = threadIdx.x, ty = threadIdx.y;
    if (z == 0) {   // cast x: 128 rows x 32 cols per block, float4-vectorized
        int tid = ty * 32 + tx;
#pragma unroll
        for (int k = 0; k < 4; ++k) {
            int slot = k * 256 + tid;
            int row = by * 128 + (slot >> 3);
            int col = bx * 32 + (slot & 7) * 4;
            float4 v = *(const float4*)&x[(size_t)row * DMODEL + col];
            bf16x4 o = {(bf16_t)v.x, (bf16_t)v.y, (bf16_t)v.z, (bf16_t)v.w};
            *(bf16x4*)&xb[(size_t)row * DMODEL + col] = o;
        }
        return;
    }
    const float* W = (z == 1) ? W0 : (z == 2) ? W1 : (z == 3) ? W2 : W3;
    bf16_t* dst = Wt + (size_t)(z - 1) * DMODEL * DMODEL;
#pragma unroll
    for (int i = 0; i < 32; i += 8)
        t[ty + i][tx] = W[(size_t)(by * 32 + ty + i) * DMODEL + bx * 32 + tx];
    __syncthreads();
#pragma unroll
    for (int i = 0; i < 32; i += 8)
        dst[(size_t)(bx * 32 + ty + i) * DMODEL + by * 32 + tx] = (bf16_t)t[tx][ty + i];
}

// ---------------------------------------------------------------- fused QKV GEMM, 128x128, BK=64
// Epilogue assembles outputs in the dead As/Bs LDS, then streams 1KB-coalesced bursts.
// ALL THREE outputs frag-major: ((bh*32 + tile)*8 + sub)*512 + lane*8 + j
__global__ __launch_bounds__(256) void gemm_qkv_kernel(const bf16_t* __restrict__ A,
                                                       const bf16_t* __restrict__ Bt,
                                                       bf16_t* __restrict__ Qfb,
                                                       bf16_t* __restrict__ Kfb,
                                                       bf16_t* __restrict__ Vfb) {
    __shared__ bf16_t sm[16384];
    bf16_t* As = sm;
    bf16_t* Bs = sm + 8192;
    int tid = threadIdx.x;
    int w = tid >> 6, l = tid & 63, g = l >> 4, lm = l & 15;
    int wr = w >> 1, wc = w & 1;
    int m0 = blockIdx.y * 128, n0 = blockIdx.x * 128;
    int r8 = l >> 3, s8 = l & 7, cw = s8 ^ r8;

    floatx4 acc[4][4];
#pragma unroll
    for (int i = 0; i < 4; ++i)
#pragma unroll
        for (int j = 0; j < 4; ++j) { floatx4 z = {0.f, 0.f, 0.f, 0.f}; acc[i][j] = z; }

    const bf16_t* Ag = A  + (size_t)(m0 + w * 32 + r8) * DMODEL + cw * 8;
    const bf16_t* Bg = Bt + (size_t)(n0 + w * 32 + r8) * DMODEL + cw * 8;

    for (int k0 = 0; k0 < DMODEL; k0 += 64) {
        __syncthreads();
#pragma unroll
        for (int j = 0; j < 4; ++j) {
            glds16(Ag + (size_t)j * 8 * DMODEL + k0, &As[(w * 32 + j * 8) * 64]);
            glds16(Bg + (size_t)j * 8 * DMODEL + k0, &Bs[(w * 32 + j * 8) * 64]);
        }
        __syncthreads();
#pragma unroll
        for (int kk = 0; kk < 2; ++kk) {
            bf16x8 af[4], bfr[4];
            int c = kk * 4 + g;
            int sw = (c ^ (lm & 7)) * 8;
#pragma unroll
            for (int i = 0; i < 4; ++i) {
                af[i]  = *(const bf16x8*)&As[(wr * 64 + i * 16 + lm) * 64 + sw];
                bfr[i] = *(const bf16x8*)&Bs[(wc * 64 + i * 16 + lm) * 64 + sw];
            }
#pragma unroll
            for (int i = 0; i < 4; ++i)
#pragma unroll
                for (int j = 0; j < 4; ++j)
                    acc[i][j] = __builtin_amdgcn_mfma_f32_16x16x32_bf16(af[i], bfr[j], acc[i][j], 0, 0, 0);
        }
    }

    __syncthreads();
    int mat = n0 >> 10;
    int headb = (n0 & 1023) >> 6;
    int b = m0 >> 11;
    int ktb = (m0 & 2047) >> 6;
    float scale = (mat == 0) ? (0.125f * LOG2E) : 1.0f;

    if (mat <= 1) {
#pragma unroll
        for (int i = 0; i < 4; ++i)
#pragma unroll
            for (int j = 0; j < 4; ++j) {
                int d = j * 16 + lm;
                int base = (wc * 2 + wr) * 4096 + (i * 2 + (d >> 5)) * 512 + ((d >> 3) & 3) * 128 + (d & 7);
#pragma unroll
                for (int r = 0; r < 4; ++r)
                    sm[base + (g * 4 + r) * 8] = (bf16_t)(acc[i][j][r] * scale);
            }
    } else {
#pragma unroll
        for (int i = 0; i < 4; ++i)
#pragma unroll
            for (int j = 0; j < 4; ++j) {
                int base = (wc * 2 + wr) * 4096 + (j * 2 + (i >> 1)) * 512 +
                           (((i & 1) * 2 + (g >> 1)) * 16 + lm) * 8 + (g & 1) * 4;
                bf16x4 pk = {(bf16_t)acc[i][j][0], (bf16_t)acc[i][j][1],
                             (bf16_t)acc[i][j][2], (bf16_t)acc[i][j][3]};
                *(bf16x4*)&sm[base] = pk;
            }
    }
    __syncthreads();
    bf16_t* outbuf = (mat == 0) ? Qfb : (mat == 1) ? Kfb : Vfb;
#pragma unroll
    for (int rep = 0; rep < 8; ++rep) {
        int idx = rep * 256 + tid;
        int c = idx >> 9;
        int off = (idx & 511) * 8;
        int bh2 = b * NHEADS + headb + (c >> 1);
        int kt = ktb + (c & 1);
        *(bf16x8*)(outbuf + ((size_t)bh2 * 32 + kt) * 4096 + off) = *(const bf16x8*)&sm[c * 4096 + off];
    }
}

// ---------------------------------------------------------------- O-proj GEMM, 64x128 tile
__global__ __launch_bounds__(256) void gemmO_kernel(const bf16_t* __restrict__ A,
                                                    const bf16_t* __restrict__ Bt,
                                                    float* __restrict__ outp) {
    __shared__ bf16_t As[64 * 64];
    __shared__ bf16_t Bs[128 * 64];
    int tid = threadIdx.x;
    int w = tid >> 6, l = tid & 63, g = l >> 4, lm = l & 15;
    int wr = w & 1, wc = w >> 1;
    int m0 = blockIdx.y * 64, n0 = blockIdx.x * 128;
    int r8 = l >> 3, s8 = l & 7, cw = s8 ^ r8;

    floatx4 acc[2][4];
#pragma unroll
    for (int i = 0; i < 2; ++i)
#pragma unroll
        for (int j = 0; j < 4; ++j) { floatx4 z = {0.f, 0.f, 0.f, 0.f}; acc[i][j] = z; }

    const bf16_t* Ag = A  + (size_t)(m0 + w * 16 + r8) * DMODEL + cw * 8;
    const bf16_t* Bg = Bt + (size_t)(n0 + w * 32 + r8) * DMODEL + cw * 8;

    for (int k0 = 0; k0 < DMODEL; k0 += 64) {
        __syncthreads();
#pragma unroll
        for (int j = 0; j < 2; ++j)
            glds16(Ag + (size_t)j * 8 * DMODEL + k0, &As[(w * 16 + j * 8) * 64]);
#pragma unroll
        for (int j = 0; j < 4; ++j)
            glds16(Bg + (size_t)j * 8 * DMODEL + k0, &Bs[(w * 32 + j * 8) * 64]);
        __syncthreads();
#pragma unroll
        for (int kk = 0; kk < 2; ++kk) {
            bf16x8 af[2], bfr[4];
            int c = kk * 4 + g;
            int sw = (c ^ (lm & 7)) * 8;
#pragma unroll
            for (int i = 0; i < 2; ++i)
                af[i] = *(const bf16x8*)&As[(wr * 32 + i * 16 + lm) * 64 + sw];
#pragma unroll
            for (int j = 0; j < 4; ++j)
                bfr[j] = *(const bf16x8*)&Bs[(wc * 64 + j * 16 + lm) * 64 + sw];
#pragma unroll
            for (int i = 0; i < 2; ++i)
#pragma unroll
                for (int j = 0; j < 4; ++j)
                    acc[i][j] = __builtin_amdgcn_mfma_f32_16x16x32_bf16(af[i], bfr[j], acc[i][j], 0, 0, 0);
        }
    }

#pragma unroll
    for (int i = 0; i < 2; ++i)
#pragma unroll
        for (int j = 0; j < 4; ++j) {
            int nc = n0 + wc * 64 + j * 16 + lm;
            int mb = m0 + wr * 32 + i * 16 + g * 4;
#pragma unroll
            for (int r = 0; r < 4; ++r)
                outp[(size_t)(mb + r) * DMODEL + nc] = acc[i][j][r];
        }
}

// ---------------------------------------------------------------- fused flash attention
// grid (32 bh, 32 qblk), block 256 = 4 waves = 4-way key split over the same 64 q rows
// (R9 structure — best measured; R10's 32q/wave halved arithmetic intensity and lost).
// Half-tile (32-key) software pipeline. Q/K/V all frag-major (every load = lane*16B).
// LDS row stride 36 elems (18 dwords): 18*lm mod 32 distinct for all 16 lm -> P writes
// conflict-free, reads <=2-3-way (~free). stride 40 had 20*8%32==0 -> lane lm/lm+8 full
// bank overlap (the measured 3.5M conflicts). DO NOT use launch_bounds (256,4): R6 spilled.
__global__ __launch_bounds__(256, 2) void attn_kernel(const bf16_t* __restrict__ Qf,
                                                      const bf16_t* __restrict__ Kf,
                                                      const bf16_t* __restrict__ Vf,
                                                      bf16_t* __restrict__ Cc) {
    __shared__ __align__(16) char smem[42496];
    bf16_t* Ps   = (bf16_t*)smem;            // loop: [w][64*36] half-P tiles (aliased under Mbuf)
    float*  Mbuf = (float*)smem;             // merge: [w][64*36]
    float*  Lbuf = (float*)(smem + 36864);   // [w][64]
    bf16_t* Ct   = (bf16_t*)(smem + 37888);  // [w][16*36] store-assembly

    int tid = threadIdx.x;
    int w = tid >> 6, l = tid & 63, g = l >> 4, lm = l & 15;
    int bh = blockIdx.x, b = bh >> 4, h = bh & 15;
    int q0 = blockIdx.y * 64;

    const bf16_t* Qfh = Qf + ((size_t)bh * 32 + (q0 >> 6)) * 4096 + l * 8;
    const bf16_t* Kfh = Kf + (size_t)bh * 32 * 4096 + l * 8;
    const bf16_t* Vfh = Vf + (size_t)bh * 32 * 4096 + l * 8;

    // Q B-frags: frag-major, 8 coalesced 1KB loads
    bf16x8 qf[4][2];
#pragma unroll
    for (int nt = 0; nt < 4; ++nt)
#pragma unroll
        for (int kk = 0; kk < 2; ++kk)
            qf[nt][kk] = *(const bf16x8*)(Qfh + (nt * 2 + kk) * 512);

    floatx4 oacc[4][4];
#pragma unroll
    for (int dt = 0; dt < 4; ++dt)
#pragma unroll
        for (int nt = 0; nt < 4; ++nt) { floatx4 z = {0.f, 0.f, 0.f, 0.f}; oacc[dt][nt] = z; }
    float lsum[4] = {0.f, 0.f, 0.f, 0.f};

    int kt0 = w * 8;
    bf16x8 kfa[2][2], kfb[2][2], vfa[4], vfb[4];
    {
        const bf16_t* Kb0 = Kfh + (size_t)kt0 * 4096;
#pragma unroll
        for (int m2 = 0; m2 < 2; ++m2)
#pragma unroll
            for (int kk = 0; kk < 2; ++kk)
                kfa[m2][kk] = *(const bf16x8*)(Kb0 + (m2 * 2 + kk) * 512);
    }

    for (int it = 0; it < 8; ++it) {
        const bf16_t* Tb = Kfh + (size_t)(kt0 + it) * 4096;
        const bf16_t* Vb = Vfh + (size_t)(kt0 + it) * 4096;
        const bf16_t* Tn = Kfh + (size_t)(kt0 + ((it < 7) ? it + 1 : 0)) * 4096;

        // loads: V half0, K half1
#pragma unroll
        for (int dt = 0; dt < 4; ++dt) vfa[dt] = *(const bf16x8*)(Vb + (dt * 2 + 0) * 512);
#pragma unroll
        for (int m2 = 0; m2 < 2; ++m2)
#pragma unroll
            for (int kk = 0; kk < 2; ++kk)
                kfb[m2][kk] = *(const bf16x8*)(Tb + (4 + m2 * 2 + kk) * 512);

        // S half0
        floatx4 sa[2][4];
#pragma unroll
        for (int m2 = 0; m2 < 2; ++m2)
#pragma unroll
            for (int nt = 0; nt < 4; ++nt) { floatx4 z = {0.f, 0.f, 0.f, 0.f}; sa[m2][nt] = z; }
#pragma unroll
        for (int kk = 0; kk < 2; ++kk)
#pragma unroll
            for (int m2 = 0; m2 < 2; ++m2)
#pragma unroll
                for (int nt = 0; nt < 4; ++nt)
                    sa[m2][nt] = __builtin_amdgcn_mfma_f32_16x16x32_bf16(kfa[m2][kk], qf[nt][kk], sa[m2][nt], 0, 0, 0);

        // loads: V half1, K half0 of next tile
#pragma unroll
        for (int dt = 0; dt < 4; ++dt) vfb[dt] = *(const bf16x8*)(Vb + (dt * 2 + 1) * 512);
#pragma unroll
        for (int m2 = 0; m2 < 2; ++m2)
#pragma unroll
            for (int kk = 0; kk < 2; ++kk)
                kfa[m2][kk] = *(const bf16x8*)(Tn + (m2 * 2 + kk) * 512);

        // S half1 — independent of exp(half0)
        floatx4 sb[2][4];
#pragma unroll
        for (int m2 = 0; m2 < 2; ++m2)
#pragma unroll
            for (int nt = 0; nt < 4; ++nt) { floatx4 z = {0.f, 0.f, 0.f, 0.f}; sb[m2][nt] = z; }
#pragma unroll
        for (int kk = 0; kk < 2; ++kk)
#pragma unroll
            for (int m2 = 0; m2 < 2; ++m2)
#pragma unroll
                for (int nt = 0; nt < 4; ++nt)
                    sb[m2][nt] = __builtin_amdgcn_mfma_f32_16x16x32_bf16(kfb[m2][kk], qf[nt][kk], sb[m2][nt], 0, 0, 0);

        // --- half0: exp + P write + PV ---
#pragma unroll
        for (int m2 = 0; m2 < 2; ++m2)
#pragma unroll
            for (int nt = 0; nt < 4; ++nt) {
                float p0 = __builtin_amdgcn_exp2f(sa[m2][nt][0]);
                float p1 = __builtin_amdgcn_exp2f(sa[m2][nt][1]);
                float p2 = __builtin_amdgcn_exp2f(sa[m2][nt][2]);
                float p3 = __builtin_amdgcn_exp2f(sa[m2][nt][3]);
                lsum[nt] += (p0 + p1) + (p2 + p3);
                bf16x4 pk = {(bf16_t)p0, (bf16_t)p1, (bf16_t)p2, (bf16_t)p3};
                *(bf16x4*)&Ps[w * 2304 + (nt * 16 + lm) * 36 + m2 * 16 + g * 4] = pk;
            }
        {
            bf16x8 bp[4];
#pragma unroll
            for (int nt = 0; nt < 4; ++nt)
                bp[nt] = *(const bf16x8*)&Ps[w * 2304 + (nt * 16 + lm) * 36 + g * 8];
#pragma unroll
            for (int dt = 0; dt < 4; ++dt)
#pragma unroll
                for (int nt = 0; nt < 4; ++nt)
                    oacc[dt][nt] = __builtin_amdgcn_mfma_f32_16x16x32_bf16(vfa[dt], bp[nt], oacc[dt][nt], 0, 0, 0);
        }

        // --- half1: exp + P write + PV ---
#pragma unroll
        for (int m2 = 0; m2 < 2; ++m2)
#pragma unroll
            for (int nt = 0; nt < 4; ++nt) {
                float p0 = __builtin_amdgcn_exp2f(sb[m2][nt][0]);
                float p1 = __builtin_amdgcn_exp2f(sb[m2][nt][1]);
                float p2 = __builtin_amdgcn_exp2f(sb[m2][nt][2]);
                float p3 = __builtin_amdgcn_exp2f(sb[m2][nt][3]);
                lsum[nt] += (p0 + p1) + (p2 + p3);
                bf16x4 pk = {(bf16_t)p0, (bf16_t)p1, (bf16_t)p2, (bf16_t)p3};
                *(bf16x4*)&Ps[w * 2304 + (nt * 16 + lm) * 36 + m2 * 16 + g * 4] = pk;
            }
        {
            bf16x8 bp[4];
#pragma unroll
            for (int nt = 0; nt < 4; ++nt)
                bp[nt] = *(const bf16x8*)&Ps[w * 2304 + (nt * 16 + lm) * 36 + g * 8];
#pragma unroll
            for (int dt = 0; dt < 4; ++dt)
#pragma unroll
                for (int nt = 0; nt < 4; ++nt)
                    oacc[dt][nt] = __builtin_amdgcn_mfma_f32_16x16x32_bf16(vfb[dt], bp[nt], oacc[dt][nt], 0, 0, 0);
        }
    }

    // reduce lsum within wave across g-groups
#pragma unroll
    for (int nt = 0; nt < 4; ++nt) {
        float s = lsum[nt];
        s += __shfl_xor(s, 16, 64);
        s += __shfl_xor(s, 32, 64);
        lsum[nt] = s;
    }

    // 4-partial merge through LDS; coalesced Cc stores via Ct
    float linv = 0.f;
#pragma unroll
    for (int p = 0; p < 2; ++p) {
        __syncthreads();
#pragma unroll
        for (int dh = 0; dh < 2; ++dh) {
            int dt = p * 2 + dh;
#pragma unroll
            for (int nt = 0; nt < 4; ++nt)
                *(floatx4*)&Mbuf[w * 2304 + (nt * 16 + lm) * 36 + dh * 16 + g * 4] = oacc[dt][nt];
        }
        if (p == 0 && g == 0)
#pragma unroll
            for (int nt = 0; nt < 4; ++nt)
                Lbuf[w * 64 + nt * 16 + lm] = lsum[nt];
        __syncthreads();
        if (p == 0) {
            float lt = 0.f;
#pragma unroll
            for (int w2 = 0; w2 < 4; ++w2)
                lt += Lbuf[w2 * 64 + w * 16 + lm];
            linv = 1.0f / lt;
        }
#pragma unroll
        for (int cc = 0; cc < 2; ++cc) {
            floatx4 s = {0.f, 0.f, 0.f, 0.f};
#pragma unroll
            for (int w2 = 0; w2 < 4; ++w2)
                s += *(const floatx4*)&Mbuf[w2 * 2304 + (w * 16 + lm) * 36 + cc * 16 + g * 4];
            bf16x4 pk = {(bf16_t)(s[0] * linv), (bf16_t)(s[1] * linv),
                         (bf16_t)(s[2] * linv), (bf16_t)(s[3] * linv)};
            *(bf16x4*)&Ct[w * 576 + lm * 36 + cc * 16 + g * 4] = pk;
        }
        // cooperative row store: 16B/lane, 64B per row
        {
            int row = l >> 2, dp = l & 3;
            bf16x8 v = *(const bf16x8*)&Ct[w * 576 + row * 36 + dp * 8];
            *(bf16x8*)&Cc[((size_t)(b * SEQ + q0 + w * 16 + row)) * DMODEL + h * DKH + p * 32 + dp * 8] = v;
        }
    }
}

// ----------------------------------------------------------------------------
extern "C" void kernel_launch(void* const* d_in, const int* in_sizes, int n_in,
                              void* d_out, int out_size, void* d_ws, size_t ws_size,
                              hipStream_t stream) {
    const float* x  = (const float*)d_in[0];
    const float* Wq = (const float*)d_in[1];
    const float* Wk = (const float*)d_in[2];
    const float* Wv = (const float*)d_in[3];
    const float* Wo = (const float*)d_in[4];

    const size_t NX = (size_t)MROWS * DMODEL;
    const size_t NW = (size_t)DMODEL * DMODEL;
    bf16_t* ws  = (bf16_t*)d_ws;
    bf16_t* xb  = ws;            // x bf16
    bf16_t* Wt  = xb + NX;       // W^T x4 contiguous: q,k,v,o
    bf16_t* Wto = Wt + 3 * NW;
    bf16_t* Qfb = Wt + 4 * NW;   // Q frag-major (B-operand), scaled log2(e)/8
    bf16_t* Kfb = Qfb + NX;      // K frag-major
    bf16_t* Vfb = Kfb + NX;      // V frag-major
    bf16_t* Cc  = Vfb + NX;      // concat

    prep_kernel<<<dim3(32, 32, 5), dim3(32, 8), 0, stream>>>(x, Wq, Wk, Wv, Wo, xb, Wt);

    gemm_qkv_kernel<<<dim3(3 * DMODEL / 128, MROWS / 128), 256, 0, stream>>>(xb, Wt, Qfb, Kfb, Vfb);

    attn_kernel<<<dim3(BATCH * NHEADS, SEQ / 64), 256, 0, stream>>>(Qfb, Kfb, Vfb, Cc);

    gemmO_kernel<<<dim3(DMODEL / 128, MROWS / 64), 256, 0, stream>>>(Cc, Wto, (float*)d_out);
}

// Round 13
// 175.728 us; speedup vs baseline: 1.0655x; 1.0379x over previous
//
#include <hip/hip_runtime.h>
#include <hip/hip_bf16.h>
#include <math.h>

#define DMODEL 1024
#define NHEADS 16
#define DKH    64
#define BATCH  2
#define SEQ    2048
#define MROWS  (BATCH * SEQ)   // 4096
#define LOG2E  1.4426950408889634f

typedef __bf16 bf16_t;
typedef bf16_t bf16x8 __attribute__((ext_vector_type(8)));
typedef bf16_t bf16x4 __attribute__((ext_vector_type(4)));
typedef float  floatx4 __attribute__((ext_vector_type(4)));

union bf16x8u { bf16x8 v8; bf16x4 v4[2]; };

// async global->LDS, 16B per lane
__device__ __forceinline__ void glds16(const bf16_t* g, bf16_t* l) {
    __builtin_amdgcn_global_load_lds((__attribute__((address_space(1))) unsigned*)(g),
                                     (__attribute__((address_space(3))) unsigned*)(l),
                                     16, 0, 0);
}

// ---------------------------------------------------------------- prep: cast x (z=0) + transpose W (z=1..4)
__global__ void prep_kernel(const float* __restrict__ x,
                            const float* __restrict__ W0, const float* __restrict__ W1,
                            const float* __restrict__ W2, const float* __restrict__ W3,
                            bf16_t* __restrict__ xb, bf16_t* __restrict__ Wt) {
    __shared__ float t[32][33];
    int bx = blockIdx.x, by = blockIdx.y, z = blockIdx.z;
    int tx = threadIdx.x, ty = threadIdx.y;
    if (z == 0) {   // cast x: 128 rows x 32 cols per block, float4-vectorized
        int tid = ty * 32 + tx;
#pragma unroll
        for (int k = 0; k < 4; ++k) {
            int slot = k * 256 + tid;
            int row = by * 128 + (slot >> 3);
            int col = bx * 32 + (slot & 7) * 4;
            float4 v = *(const float4*)&x[(size_t)row * DMODEL + col];
            bf16x4 o = {(bf16_t)v.x, (bf16_t)v.y, (bf16_t)v.z, (bf16_t)v.w};
            *(bf16x4*)&xb[(size_t)row * DMODEL + col] = o;
        }
        return;
    }
    const float* W = (z == 1) ? W0 : (z == 2) ? W1 : (z == 3) ? W2 : W3;
    bf16_t* dst = Wt + (size_t)(z - 1) * DMODEL * DMODEL;
#pragma unroll
    for (int i = 0; i < 32; i += 8)
        t[ty + i][tx] = W[(size_t)(by * 32 + ty + i) * DMODEL + bx * 32 + tx];
    __syncthreads();
#pragma unroll
    for (int i = 0; i < 32; i += 8)
        dst[(size_t)(bx * 32 + ty + i) * DMODEL + by * 32 + tx] = (bf16_t)t[tx][ty + i];
}

// ---------------------------------------------------------------- fused QKV GEMM, 128x128, BK=64
// Epilogue assembles outputs in the dead As/Bs LDS, then streams 1KB-coalesced bursts.
// ALL THREE outputs frag-major: ((bh*32 + tile)*8 + sub)*512 + lane*8 + j
__global__ __launch_bounds__(256) void gemm_qkv_kernel(const bf16_t* __restrict__ A,
                                                       const bf16_t* __restrict__ Bt,
                                                       bf16_t* __restrict__ Qfb,
                                                       bf16_t* __restrict__ Kfb,
                                                       bf16_t* __restrict__ Vfb) {
    __shared__ bf16_t sm[16384];
    bf16_t* As = sm;
    bf16_t* Bs = sm + 8192;
    int tid = threadIdx.x;
    int w = tid >> 6, l = tid & 63, g = l >> 4, lm = l & 15;
    int wr = w >> 1, wc = w & 1;
    int m0 = blockIdx.y * 128, n0 = blockIdx.x * 128;
    int r8 = l >> 3, s8 = l & 7, cw = s8 ^ r8;

    floatx4 acc[4][4];
#pragma unroll
    for (int i = 0; i < 4; ++i)
#pragma unroll
        for (int j = 0; j < 4; ++j) { floatx4 z = {0.f, 0.f, 0.f, 0.f}; acc[i][j] = z; }

    const bf16_t* Ag = A  + (size_t)(m0 + w * 32 + r8) * DMODEL + cw * 8;
    const bf16_t* Bg = Bt + (size_t)(n0 + w * 32 + r8) * DMODEL + cw * 8;

    for (int k0 = 0; k0 < DMODEL; k0 += 64) {
        __syncthreads();
#pragma unroll
        for (int j = 0; j < 4; ++j) {
            glds16(Ag + (size_t)j * 8 * DMODEL + k0, &As[(w * 32 + j * 8) * 64]);
            glds16(Bg + (size_t)j * 8 * DMODEL + k0, &Bs[(w * 32 + j * 8) * 64]);
        }
        __syncthreads();
#pragma unroll
        for (int kk = 0; kk < 2; ++kk) {
            bf16x8 af[4], bfr[4];
            int c = kk * 4 + g;
            int sw = (c ^ (lm & 7)) * 8;
#pragma unroll
            for (int i = 0; i < 4; ++i) {
                af[i]  = *(const bf16x8*)&As[(wr * 64 + i * 16 + lm) * 64 + sw];
                bfr[i] = *(const bf16x8*)&Bs[(wc * 64 + i * 16 + lm) * 64 + sw];
            }
#pragma unroll
            for (int i = 0; i < 4; ++i)
#pragma unroll
                for (int j = 0; j < 4; ++j)
                    acc[i][j] = __builtin_amdgcn_mfma_f32_16x16x32_bf16(af[i], bfr[j], acc[i][j], 0, 0, 0);
        }
    }

    __syncthreads();
    int mat = n0 >> 10;
    int headb = (n0 & 1023) >> 6;
    int b = m0 >> 11;
    int ktb = (m0 & 2047) >> 6;
    float scale = (mat == 0) ? (0.125f * LOG2E) : 1.0f;

    if (mat <= 1) {
#pragma unroll
        for (int i = 0; i < 4; ++i)
#pragma unroll
            for (int j = 0; j < 4; ++j) {
                int d = j * 16 + lm;
                int base = (wc * 2 + wr) * 4096 + (i * 2 + (d >> 5)) * 512 + ((d >> 3) & 3) * 128 + (d & 7);
#pragma unroll
                for (int r = 0; r < 4; ++r)
                    sm[base + (g * 4 + r) * 8] = (bf16_t)(acc[i][j][r] * scale);
            }
    } else {
#pragma unroll
        for (int i = 0; i < 4; ++i)
#pragma unroll
            for (int j = 0; j < 4; ++j) {
                int base = (wc * 2 + wr) * 4096 + (j * 2 + (i >> 1)) * 512 +
                           (((i & 1) * 2 + (g >> 1)) * 16 + lm) * 8 + (g & 1) * 4;
                bf16x4 pk = {(bf16_t)acc[i][j][0], (bf16_t)acc[i][j][1],
                             (bf16_t)acc[i][j][2], (bf16_t)acc[i][j][3]};
                *(bf16x4*)&sm[base] = pk;
            }
    }
    __syncthreads();
    bf16_t* outbuf = (mat == 0) ? Qfb : (mat == 1) ? Kfb : Vfb;
#pragma unroll
    for (int rep = 0; rep < 8; ++rep) {
        int idx = rep * 256 + tid;
        int c = idx >> 9;
        int off = (idx & 511) * 8;
        int bh2 = b * NHEADS + headb + (c >> 1);
        int kt = ktb + (c & 1);
        *(bf16x8*)(outbuf + ((size_t)bh2 * 32 + kt) * 4096 + off) = *(const bf16x8*)&sm[c * 4096 + off];
    }
}

// ---------------------------------------------------------------- O-proj GEMM, 64x128 tile
__global__ __launch_bounds__(256) void gemmO_kernel(const bf16_t* __restrict__ A,
                                                    const bf16_t* __restrict__ Bt,
                                                    float* __restrict__ outp) {
    __shared__ bf16_t As[64 * 64];
    __shared__ bf16_t Bs[128 * 64];
    int tid = threadIdx.x;
    int w = tid >> 6, l = tid & 63, g = l >> 4, lm = l & 15;
    int wr = w & 1, wc = w >> 1;
    int m0 = blockIdx.y * 64, n0 = blockIdx.x * 128;
    int r8 = l >> 3, s8 = l & 7, cw = s8 ^ r8;

    floatx4 acc[2][4];
#pragma unroll
    for (int i = 0; i < 2; ++i)
#pragma unroll
        for (int j = 0; j < 4; ++j) { floatx4 z = {0.f, 0.f, 0.f, 0.f}; acc[i][j] = z; }

    const bf16_t* Ag = A  + (size_t)(m0 + w * 16 + r8) * DMODEL + cw * 8;
    const bf16_t* Bg = Bt + (size_t)(n0 + w * 32 + r8) * DMODEL + cw * 8;

    for (int k0 = 0; k0 < DMODEL; k0 += 64) {
        __syncthreads();
#pragma unroll
        for (int j = 0; j < 2; ++j)
            glds16(Ag + (size_t)j * 8 * DMODEL + k0, &As[(w * 16 + j * 8) * 64]);
#pragma unroll
        for (int j = 0; j < 4; ++j)
            glds16(Bg + (size_t)j * 8 * DMODEL + k0, &Bs[(w * 32 + j * 8) * 64]);
        __syncthreads();
#pragma unroll
        for (int kk = 0; kk < 2; ++kk) {
            bf16x8 af[2], bfr[4];
            int c = kk * 4 + g;
            int sw = (c ^ (lm & 7)) * 8;
#pragma unroll
            for (int i = 0; i < 2; ++i)
                af[i] = *(const bf16x8*)&As[(wr * 32 + i * 16 + lm) * 64 + sw];
#pragma unroll
            for (int j = 0; j < 4; ++j)
                bfr[j] = *(const bf16x8*)&Bs[(wc * 64 + j * 16 + lm) * 64 + sw];
#pragma unroll
            for (int i = 0; i < 2; ++i)
#pragma unroll
                for (int j = 0; j < 4; ++j)
                    acc[i][j] = __builtin_amdgcn_mfma_f32_16x16x32_bf16(af[i], bfr[j], acc[i][j], 0, 0, 0);
        }
    }

#pragma unroll
    for (int i = 0; i < 2; ++i)
#pragma unroll
        for (int j = 0; j < 4; ++j) {
            int nc = n0 + wc * 64 + j * 16 + lm;
            int mb = m0 + wr * 32 + i * 16 + g * 4;
#pragma unroll
            for (int r = 0; r < 4; ++r)
                outp[(size_t)(mb + r) * DMODEL + nc] = acc[i][j][r];
        }
}

// ---------------------------------------------------------------- fused flash attention
// grid (32 bh, 32 qblk), block 256 = 4 waves = 4-way key split over the same 64 q rows.
// Half-tile (32-key) software pipeline. Q/K/V all frag-major (every load = lane*16B).
// LDS row stride 36 elems: bank-clean writes (18*lm mod 32 distinct; R11 measured 262K
// conflicts vs 3.5M at stride 40) BUT 72B rows are 8-mod-16 for odd lm -> b128 reads
// were misaligned/split (R11's +5us). Fix: P and Ct reads are PAIRED ds_read_b64
// (byte offsets 72*row+16g, +8 -> both 8-aligned). DO NOT use launch_bounds (256,4): R6 spilled.
__global__ __launch_bounds__(256, 2) void attn_kernel(const bf16_t* __restrict__ Qf,
                                                      const bf16_t* __restrict__ Kf,
                                                      const bf16_t* __restrict__ Vf,
                                                      bf16_t* __restrict__ Cc) {
    __shared__ __align__(16) char smem[42496];
    bf16_t* Ps   = (bf16_t*)smem;            // loop: [w][64*36] half-P tiles (aliased under Mbuf)
    float*  Mbuf = (float*)smem;             // merge: [w][64*36]
    float*  Lbuf = (float*)(smem + 36864);   // [w][64]
    bf16_t* Ct   = (bf16_t*)(smem + 37888);  // [w][16*36] store-assembly

    int tid = threadIdx.x;
    int w = tid >> 6, l = tid & 63, g = l >> 4, lm = l & 15;
    int bh = blockIdx.x, b = bh >> 4, h = bh & 15;
    int q0 = blockIdx.y * 64;

    const bf16_t* Qfh = Qf + ((size_t)bh * 32 + (q0 >> 6)) * 4096 + l * 8;
    const bf16_t* Kfh = Kf + (size_t)bh * 32 * 4096 + l * 8;
    const bf16_t* Vfh = Vf + (size_t)bh * 32 * 4096 + l * 8;

    // Q B-frags: frag-major, 8 coalesced 1KB loads
    bf16x8 qf[4][2];
#pragma unroll
    for (int nt = 0; nt < 4; ++nt)
#pragma unroll
        for (int kk = 0; kk < 2; ++kk)
            qf[nt][kk] = *(const bf16x8*)(Qfh + (nt * 2 + kk) * 512);

    floatx4 oacc[4][4];
#pragma unroll
    for (int dt = 0; dt < 4; ++dt)
#pragma unroll
        for (int nt = 0; nt < 4; ++nt) { floatx4 z = {0.f, 0.f, 0.f, 0.f}; oacc[dt][nt] = z; }
    float lsum[4] = {0.f, 0.f, 0.f, 0.f};

    int kt0 = w * 8;
    bf16x8 kfa[2][2], kfb[2][2], vfa[4], vfb[4];
    {
        const bf16_t* Kb0 = Kfh + (size_t)kt0 * 4096;
#pragma unroll
        for (int m2 = 0; m2 < 2; ++m2)
#pragma unroll
            for (int kk = 0; kk < 2; ++kk)
                kfa[m2][kk] = *(const bf16x8*)(Kb0 + (m2 * 2 + kk) * 512);
    }

    for (int it = 0; it < 8; ++it) {
        const bf16_t* Tb = Kfh + (size_t)(kt0 + it) * 4096;
        const bf16_t* Vb = Vfh + (size_t)(kt0 + it) * 4096;
        const bf16_t* Tn = Kfh + (size_t)(kt0 + ((it < 7) ? it + 1 : 0)) * 4096;

        // loads: V half0, K half1
#pragma unroll
        for (int dt = 0; dt < 4; ++dt) vfa[dt] = *(const bf16x8*)(Vb + (dt * 2 + 0) * 512);
#pragma unroll
        for (int m2 = 0; m2 < 2; ++m2)
#pragma unroll
            for (int kk = 0; kk < 2; ++kk)
                kfb[m2][kk] = *(const bf16x8*)(Tb + (4 + m2 * 2 + kk) * 512);

        // S half0
        floatx4 sa[2][4];
#pragma unroll
        for (int m2 = 0; m2 < 2; ++m2)
#pragma unroll
            for (int nt = 0; nt < 4; ++nt) { floatx4 z = {0.f, 0.f, 0.f, 0.f}; sa[m2][nt] = z; }
#pragma unroll
        for (int kk = 0; kk < 2; ++kk)
#pragma unroll
            for (int m2 = 0; m2 < 2; ++m2)
#pragma unroll
                for (int nt = 0; nt < 4; ++nt)
                    sa[m2][nt] = __builtin_amdgcn_mfma_f32_16x16x32_bf16(kfa[m2][kk], qf[nt][kk], sa[m2][nt], 0, 0, 0);

        // loads: V half1, K half0 of next tile
#pragma unroll
        for (int dt = 0; dt < 4; ++dt) vfb[dt] = *(const bf16x8*)(Vb + (dt * 2 + 1) * 512);
#pragma unroll
        for (int m2 = 0; m2 < 2; ++m2)
#pragma unroll
            for (int kk = 0; kk < 2; ++kk)
                kfa[m2][kk] = *(const bf16x8*)(Tn + (m2 * 2 + kk) * 512);

        // S half1 — independent of exp(half0)
        floatx4 sb[2][4];
#pragma unroll
        for (int m2 = 0; m2 < 2; ++m2)
#pragma unroll
            for (int nt = 0; nt < 4; ++nt) { floatx4 z = {0.f, 0.f, 0.f, 0.f}; sb[m2][nt] = z; }
#pragma unroll
        for (int kk = 0; kk < 2; ++kk)
#pragma unroll
            for (int m2 = 0; m2 < 2; ++m2)
#pragma unroll
                for (int nt = 0; nt < 4; ++nt)
                    sb[m2][nt] = __builtin_amdgcn_mfma_f32_16x16x32_bf16(kfb[m2][kk], qf[nt][kk], sb[m2][nt], 0, 0, 0);

        // --- half0: exp + P write + PV ---
#pragma unroll
        for (int m2 = 0; m2 < 2; ++m2)
#pragma unroll
            for (int nt = 0; nt < 4; ++nt) {
                float p0 = __builtin_amdgcn_exp2f(sa[m2][nt][0]);
                float p1 = __builtin_amdgcn_exp2f(sa[m2][nt][1]);
                float p2 = __builtin_amdgcn_exp2f(sa[m2][nt][2]);
                float p3 = __builtin_amdgcn_exp2f(sa[m2][nt][3]);
                lsum[nt] += (p0 + p1) + (p2 + p3);
                bf16x4 pk = {(bf16_t)p0, (bf16_t)p1, (bf16_t)p2, (bf16_t)p3};
                *(bf16x4*)&Ps[w * 2304 + (nt * 16 + lm) * 36 + m2 * 16 + g * 4] = pk;
            }
        {
            bf16x8u bp[4];
#pragma unroll
            for (int nt = 0; nt < 4; ++nt) {
                bp[nt].v4[0] = *(const bf16x4*)&Ps[w * 2304 + (nt * 16 + lm) * 36 + g * 8];
                bp[nt].v4[1] = *(const bf16x4*)&Ps[w * 2304 + (nt * 16 + lm) * 36 + g * 8 + 4];
            }
#pragma unroll
            for (int dt = 0; dt < 4; ++dt)
#pragma unroll
                for (int nt = 0; nt < 4; ++nt)
                    oacc[dt][nt] = __builtin_amdgcn_mfma_f32_16x16x32_bf16(vfa[dt], bp[nt].v8, oacc[dt][nt], 0, 0, 0);
        }

        // --- half1: exp + P write + PV ---
#pragma unroll
        for (int m2 = 0; m2 < 2; ++m2)
#pragma unroll
            for (int nt = 0; nt < 4; ++nt) {
                float p0 = __builtin_amdgcn_exp2f(sb[m2][nt][0]);
                float p1 = __builtin_amdgcn_exp2f(sb[m2][nt][1]);
                float p2 = __builtin_amdgcn_exp2f(sb[m2][nt][2]);
                float p3 = __builtin_amdgcn_exp2f(sb[m2][nt][3]);
                lsum[nt] += (p0 + p1) + (p2 + p3);
                bf16x4 pk = {(bf16_t)p0, (bf16_t)p1, (bf16_t)p2, (bf16_t)p3};
                *(bf16x4*)&Ps[w * 2304 + (nt * 16 + lm) * 36 + m2 * 16 + g * 4] = pk;
            }
        {
            bf16x8u bp[4];
#pragma unroll
            for (int nt = 0; nt < 4; ++nt) {
                bp[nt].v4[0] = *(const bf16x4*)&Ps[w * 2304 + (nt * 16 + lm) * 36 + g * 8];
                bp[nt].v4[1] = *(const bf16x4*)&Ps[w * 2304 + (nt * 16 + lm) * 36 + g * 8 + 4];
            }
#pragma unroll
            for (int dt = 0; dt < 4; ++dt)
#pragma unroll
                for (int nt = 0; nt < 4; ++nt)
                    oacc[dt][nt] = __builtin_amdgcn_mfma_f32_16x16x32_bf16(vfb[dt], bp[nt].v8, oacc[dt][nt], 0, 0, 0);
        }
    }

    // reduce lsum within wave across g-groups
#pragma unroll
    for (int nt = 0; nt < 4; ++nt) {
        float s = lsum[nt];
        s += __shfl_xor(s, 16, 64);
        s += __shfl_xor(s, 32, 64);
        lsum[nt] = s;
    }

    // 4-partial merge through LDS; coalesced Cc stores via Ct
    float linv = 0.f;
#pragma unroll
    for (int p = 0; p < 2; ++p) {
        __syncthreads();
#pragma unroll
        for (int dh = 0; dh < 2; ++dh) {
            int dt = p * 2 + dh;
#pragma unroll
            for (int nt = 0; nt < 4; ++nt)
                *(floatx4*)&Mbuf[w * 2304 + (nt * 16 + lm) * 36 + dh * 16 + g * 4] = oacc[dt][nt];
        }
        if (p == 0 && g == 0)
#pragma unroll
            for (int nt = 0; nt < 4; ++nt)
                Lbuf[w * 64 + nt * 16 + lm] = lsum[nt];
        __syncthreads();
        if (p == 0) {
            float lt = 0.f;
#pragma unroll
            for (int w2 = 0; w2 < 4; ++w2)
                lt += Lbuf[w2 * 64 + w * 16 + lm];
            linv = 1.0f / lt;
        }
#pragma unroll
        for (int cc = 0; cc < 2; ++cc) {
            floatx4 s = {0.f, 0.f, 0.f, 0.f};
#pragma unroll
            for (int w2 = 0; w2 < 4; ++w2)
                s += *(const floatx4*)&Mbuf[w2 * 2304 + (w * 16 + lm) * 36 + cc * 16 + g * 4];
            bf16x4 pk = {(bf16_t)(s[0] * linv), (bf16_t)(s[1] * linv),
                         (bf16_t)(s[2] * linv), (bf16_t)(s[3] * linv)};
            *(bf16x4*)&Ct[w * 576 + lm * 36 + cc * 16 + g * 4] = pk;
        }
        // cooperative row store: paired b64 LDS reads (8-aligned), 16B/lane global store
        {
            int row = l >> 2, dp = l & 3;
            bf16x8u v;
            v.v4[0] = *(const bf16x4*)&Ct[w * 576 + row * 36 + dp * 8];
            v.v4[1] = *(const bf16x4*)&Ct[w * 576 + row * 36 + dp * 8 + 4];
            *(bf16x8*)&Cc[((size_t)(b * SEQ + q0 + w * 16 + row)) * DMODEL + h * DKH + p * 32 + dp * 8] = v.v8;
        }
    }
}

// ----------------------------------------------------------------------------
extern "C" void kernel_launch(void* const* d_in, const int* in_sizes, int n_in,
                              void* d_out, int out_size, void* d_ws, size_t ws_size,
                              hipStream_t stream) {
    const float* x  = (const float*)d_in[0];
    const float* Wq = (const float*)d_in[1];
    const float* Wk = (const float*)d_in[2];
    const float* Wv = (const float*)d_in[3];
    const float* Wo = (const float*)d_in[4];

    const size_t NX = (size_t)MROWS * DMODEL;
    const size_t NW = (size_t)DMODEL * DMODEL;
    bf16_t* ws  = (bf16_t*)d_ws;
    bf16_t* xb  = ws;            // x bf16
    bf16_t* Wt  = xb + NX;       // W^T x4 contiguous: q,k,v,o
    bf16_t* Wto = Wt + 3 * NW;
    bf16_t* Qfb = Wt + 4 * NW;   // Q frag-major (B-operand), scaled log2(e)/8
    bf16_t* Kfb = Qfb + NX;      // K frag-major
    bf16_t* Vfb = Kfb + NX;      // V frag-major
    bf16_t* Cc  = Vfb + NX;      // concat

    prep_kernel<<<dim3(32, 32, 5), dim3(32, 8), 0, stream>>>(x, Wq, Wk, Wv, Wo, xb, Wt);

    gemm_qkv_kernel<<<dim3(3 * DMODEL / 128, MROWS / 128), 256, 0, stream>>>(xb, Wt, Qfb, Kfb, Vfb);

    attn_kernel<<<dim3(BATCH * NHEADS, SEQ / 64), 256, 0, stream>>>(Qfb, Kfb, Vfb, Cc);

    gemmO_kernel<<<dim3(DMODEL / 128, MROWS / 64), 256, 0, stream>>>(Cc, Wto, (float*)d_out);
}